// Round 2
// baseline (201.559 us; speedup 1.0000x reference)
//
#include <hip/hip_runtime.h>
#include <hip/hip_fp16.h>

// Problem constants (DirectedGraphLayer): B=2, N=50000, FIN=128, FOUT=64, E=800000
#define Bc   2
#define Nn   50000
#define FINc 128
#define FOUTc 64
#define Mtot (Bc * Nn)          // 100000 combined (b,n) rows
#define CCOMB 128               // combined feature cols: [W cols 0..63 | W_self cols 0..63]
#define GB 1563                 // gemm tiles: ceil(100000/64)
#define SB 1563                 // scatter chunks at 2 edges/thread: ceil(800000/512)
#define NGRP 392                // role groups of 8 blocks: 196 scatter + 196 gemm (>=1563 each)
#define CAP 64                  // per-row edge capacity, 256 B line-aligned (P(Poisson16>64)~1e-17)
#define ZTOT (Nn * 16)          // ints to zero: cntp

typedef __bf16 bf16x8 __attribute__((ext_vector_type(8)));
typedef float  f32x4  __attribute__((ext_vector_type(4)));

static __device__ inline unsigned short f2bf(float f) {
    unsigned int u = __float_as_uint(f);
    u += 0x7fffu + ((u >> 16) & 1u);       // round-to-nearest-even
    return (unsigned short)(u >> 16);
}

// ---------------------------------------------------------------------------
// prep: blocks 0..7 pack [W|W_self] -> fragment-major bf16 (MFMA A-operand
// layout); blocks 8+ zero cntp.
// ---------------------------------------------------------------------------
__global__ __launch_bounds__(256) void prep(
    const float* __restrict__ W, const float* __restrict__ Ws,
    unsigned short* __restrict__ Bp, int* __restrict__ zbase)
{
    if (blockIdx.x < 8) {
        const int idx = blockIdx.x * 256 + threadIdx.x;
        const int lane = idx & 63;
        const int kt   = (idx >> 6) & 3;
        const int nt   = idx >> 8;
        const int n    = nt * 16 + (lane & 15);
        const int k0   = kt * 32 + (lane >> 4) * 8;
        unsigned short o8[8];
#pragma unroll
        for (int j = 0; j < 8; ++j) {
            const int f = k0 + j;
            const float v = (n < 64) ? W[f * FOUTc + n] : Ws[f * FOUTc + (n - 64)];
            o8[j] = f2bf(v);
        }
        *(uint4*)&Bp[(size_t)idx * 8] = *(uint4*)o8;
    } else {
        const int i4 = (blockIdx.x - 8) * 1024 + threadIdx.x * 4;
        if (i4 + 4 <= ZTOT)
            *(int4*)&zbase[i4] = make_int4(0, 0, 0, 0);
    }
}

// ---------------------------------------------------------------------------
// scatter_gemm: INTERLEAVED fusion, role assigned per GROUP OF 8 blocks.
// blockIdx % 8 maps round-robin to XCDs; the previous parity-based role
// split put all scatter blocks on even XCDs and all gemm blocks on odd
// XCDs, so the intended per-CU overlap never happened. Group-of-8 role
// assignment gives every XCD an alternating stream of both roles.
//   scatter groups (g even) -> one 512-edge chunk per block (2 atomic
//     chains per lane; latency hides under co-resident gemm blocks)
//   gemm groups (g odd) -> one 64-row MFMA tile (A=weights, B=x)
//     gemm cols 0..63  -> xrb (bf16, (N, B*64) layout)
//     gemm cols 64..127-> outp pre-ReLU self term (+bias, f32)
// cvp segments are 256 B line-aligned (CAP=64).
// ---------------------------------------------------------------------------
__global__ __launch_bounds__(256) void scatter_gemm(
    const float* __restrict__ x, const unsigned short* __restrict__ Bp,
    const float* __restrict__ bself,
    unsigned short* __restrict__ xrb, float* __restrict__ outp,
    const int* __restrict__ erow, const int* __restrict__ ecol,
    const float* __restrict__ evalv, int* __restrict__ cntp,
    unsigned int* __restrict__ cvp, int E)
{
    const int g   = blockIdx.x >> 3;                 // group of 8 (one per XCD)
    const int sub = blockIdx.x & 7;
    const int ord = (g >> 1) * 8 + sub;              // ordinal within role

    if (!(g & 1)) {
        // ---- scatter chunk: edges [ord*512, ord*512+512), 2 per thread ----
        if (ord >= SB) return;
        const int e0 = ord * 512 + threadIdx.x;
        const int e1 = e0 + 256;
        if (e0 < E) {
            const int   r = erow[e0];
            const int   c = ecol[e0];
            const float v = evalv[e0];
            const int k = atomicAdd(&cntp[(size_t)r * 16], 1);
            if (k < CAP)
                cvp[((size_t)r << 6) + k] =
                    ((unsigned int)__half_as_ushort(__float2half(v)) << 17) | (unsigned int)c;
        }
        if (e1 < E) {
            const int   r = erow[e1];
            const int   c = ecol[e1];
            const float v = evalv[e1];
            const int k = atomicAdd(&cntp[(size_t)r * 16], 1);
            if (k < CAP)
                cvp[((size_t)r << 6) + k] =
                    ((unsigned int)__half_as_ushort(__float2half(v)) << 17) | (unsigned int)c;
        }
        return;
    }

    // ---- gemm tile ----
    if (ord >= GB) return;
    const int gb   = ord;                    // 0..1562
    const int lane = threadIdx.x & 63;
    const int quad = lane >> 4;
    const int mbase = gb * 64 + (threadIdx.x >> 6) * 16;

    const int mrow   = mbase + (lane & 15);
    const int mclamp = (mrow < Mtot) ? mrow : (Mtot - 1);
    const float* __restrict__ xrow = &x[(size_t)mclamp * FINc + quad * 8];

    float4 xv[8];
#pragma unroll
    for (int kt = 0; kt < 4; ++kt) {
        xv[2 * kt]     = *(const float4*)&xrow[kt * 32];
        xv[2 * kt + 1] = *(const float4*)&xrow[kt * 32 + 4];
    }

    f32x4 acc[8] = {};

#pragma unroll
    for (int kt = 0; kt < 4; ++kt) {
        const float4 xa = xv[2 * kt];
        const float4 xb = xv[2 * kt + 1];
        bf16x8 bf;                       // B operand: B[k][m], m=lane&15
        bf[0] = (__bf16)xa.x; bf[1] = (__bf16)xa.y;
        bf[2] = (__bf16)xa.z; bf[3] = (__bf16)xa.w;
        bf[4] = (__bf16)xb.x; bf[5] = (__bf16)xb.y;
        bf[6] = (__bf16)xb.z; bf[7] = (__bf16)xb.w;

        const bf16x8* __restrict__ abase =
            (const bf16x8*)&Bp[(size_t)(kt * 64 + lane) * 8];
#pragma unroll
        for (int nt = 0; nt < 8; ++nt) {
            const bf16x8 af = abase[nt * 4 * 64];   // entry (nt*4+kt)*64+lane
            acc[nt] = __builtin_amdgcn_mfma_f32_16x16x32_bf16(af, bf, acc[nt], 0, 0, 0);
        }
    }

    const int m = mbase + (lane & 15);
    if (m < Mtot) {
        const int bb = (m >= Nn) ? 1 : 0;
        const int n = m - bb * Nn;
        unsigned short* __restrict__ xp = &xrb[(size_t)n * CCOMB + bb * FOUTc];
        const int cq = quad * 4;
#pragma unroll
        for (int nt = 0; nt < 4; ++nt) {
            const int c = nt * 16 + cq;
            unsigned short h[4];
            h[0] = f2bf(acc[nt][0]); h[1] = f2bf(acc[nt][1]);
            h[2] = f2bf(acc[nt][2]); h[3] = f2bf(acc[nt][3]);
            *(uint2*)&xp[c] = *(uint2*)h;           // 8 B store
        }
        float* __restrict__ op = &outp[(size_t)m * FOUTc];
#pragma unroll
        for (int nt = 4; nt < 8; ++nt) {
            const int o = (nt - 4) * 16 + cq;
            const float4 b4 = *(const float4*)&bself[o];
            float4 v;
            v.x = acc[nt][0] + b4.x; v.y = acc[nt][1] + b4.y;
            v.z = acc[nt][2] + b4.z; v.w = acc[nt][3] + b4.w;
            *(float4*)&op[o] = v;                   // 16 B store, line-dense
        }
    }
}

// ---------------------------------------------------------------------------
// row_gather: XCD-affine half-row jobs. Fixed-CAP (64, line-aligned) layout:
// first 16 edge words (one 64 B line) have KNOWN addresses -> cvp[slot],
// cvp[8+slot], count all load in parallel; gather xrb speculatively; zero
// multiplier for slots >= count. Fused finalize: out = relu(self_pre + agg).
// ---------------------------------------------------------------------------
#define GATHP(W, PRED, ACC)                                                   \
    {                                                                         \
        const unsigned int w = (W);                                           \
        unsigned int col = w & 0x1FFFFu;                                      \
        col = (col < Nn) ? col : 0u;       /* clamp speculative garbage */    \
        const float vv = (PRED) ? __half2float(__ushort_as_half(              \
                             (unsigned short)(w >> 17))) : 0.0f;              \
        const uint4 raw = *(const uint4*)&xrb[(size_t)col * CCOMB + c0];      \
        ACC[0] = fmaf(vv, __uint_as_float(raw.x << 16),         ACC[0]);      \
        ACC[1] = fmaf(vv, __uint_as_float(raw.x & 0xffff0000u), ACC[1]);      \
        ACC[2] = fmaf(vv, __uint_as_float(raw.y << 16),         ACC[2]);      \
        ACC[3] = fmaf(vv, __uint_as_float(raw.y & 0xffff0000u), ACC[3]);      \
        ACC[4] = fmaf(vv, __uint_as_float(raw.z << 16),         ACC[4]);      \
        ACC[5] = fmaf(vv, __uint_as_float(raw.z & 0xffff0000u), ACC[5]);      \
        ACC[6] = fmaf(vv, __uint_as_float(raw.w << 16),         ACC[6]);      \
        ACC[7] = fmaf(vv, __uint_as_float(raw.w & 0xffff0000u), ACC[7]);      \
    }

__global__ __launch_bounds__(256) void row_gather(
    const int* __restrict__ cntp, const unsigned int* __restrict__ cvp,
    const unsigned short* __restrict__ xrb, float* __restrict__ outp)
{
    const int j    = blockIdx.x;
    const int low3 = j & 7;
    const int h    = (low3 >= 4) ? 1 : 0;      // batch half -> XCD group
    const int ord  = (j >> 3) * 4 + (low3 & 3);
    int n = ord * 4 + (threadIdx.x >> 6);
    n = __builtin_amdgcn_readfirstlane(n);     // wave-uniform -> scalar loads

    const int lane = threadIdx.x & 63;
    const int slot = lane >> 3;                // edge slot 0..7
    const int c0   = h * 64 + (lane & 7) * 8;  // 8 combined cols per lane
    const unsigned int* __restrict__ seg = &cvp[(size_t)n << 6];

    // three independent loads issue together
    const int kc = min(cntp[(size_t)n * 16], CAP);
    const unsigned int u0 = seg[slot];
    const unsigned int u1 = seg[8 + slot];

    float aA[8] = {0.f, 0.f, 0.f, 0.f, 0.f, 0.f, 0.f, 0.f};

    GATHP(u0, slot < kc,     aA);
    GATHP(u1, slot + 8 < kc, aA);

    for (int e = 16 + slot; e < kc; e += 8) {
        const unsigned int u = seg[e];
        GATHP(u, true, aA);
    }

#pragma unroll
    for (int i = 0; i < 8; ++i) {
        aA[i] += __shfl_down(aA[i], 8);
        aA[i] += __shfl_down(aA[i], 16);
        aA[i] += __shfl_down(aA[i], 32);
    }

    if (lane < 8) {
        const size_t m = (size_t)h * Nn + n;
        const int o = lane * 8;                // feature offset within 64
        float* __restrict__ op = &outp[m * FOUTc + o];
        float4 s0 = *(float4*)&op[0];
        float4 s1 = *(float4*)&op[4];
        s0.x = fmaxf(s0.x + aA[0], 0.0f); s0.y = fmaxf(s0.y + aA[1], 0.0f);
        s0.z = fmaxf(s0.z + aA[2], 0.0f); s0.w = fmaxf(s0.w + aA[3], 0.0f);
        s1.x = fmaxf(s1.x + aA[4], 0.0f); s1.y = fmaxf(s1.y + aA[5], 0.0f);
        s1.z = fmaxf(s1.z + aA[6], 0.0f); s1.w = fmaxf(s1.w + aA[7], 0.0f);
        *(float4*)&op[0] = s0;
        *(float4*)&op[4] = s1;
    }
}

extern "C" void kernel_launch(void* const* d_in, const int* in_sizes, int n_in,
                              void* d_out, int out_size, void* d_ws, size_t ws_size,
                              hipStream_t stream)
{
    const float* x    = (const float*)d_in[0];
    const float* W    = (const float*)d_in[1];
    const float* Ws   = (const float*)d_in[2];
    const float* bs   = (const float*)d_in[3];
    const int*   erow = (const int*)d_in[4];
    const int*   ecol = (const int*)d_in[5];
    const float* eval = (const float*)d_in[6];
    float* outp = (float*)d_out;
    const int E = in_sizes[4];

    // workspace layout (~29 MB total; all bases 256 B aligned by construction)
    unsigned short* xrb = (unsigned short*)d_ws;            // N*128 bf16 = 12.8 MB
    unsigned int*   cvp = (unsigned int*)(xrb + (size_t)Nn * CCOMB); // N*64 u32 = 12.8 MB
    int*            cntp = (int*)(cvp + ((size_t)Nn << 6)); // N*16 ints = 3.2 MB
    unsigned short* Bp  = (unsigned short*)(cntp + (size_t)Nn * 16); // 32 KB

    // 1. pack weights + zero padded counters
    prep<<<8 + (ZTOT + 1023) / 1024, 256, 0, stream>>>(W, Ws, Bp, cntp);

    // 2. fused interleave: group-of-8 role split so every XCD sees both roles
    scatter_gemm<<<NGRP * 8, 256, 0, stream>>>(x, Bp, bs, xrb, outp,
                                               erow, ecol, eval, cntp, cvp, E);

    // 3. per-half-row speculative gather-reduce fused with finalize
    row_gather<<<Nn / 2, 256, 0, stream>>>(cntp, cvp, xrb, outp);
}

// Round 3
// 185.271 us; speedup vs baseline: 1.0879x; 1.0879x over previous
//
#include <hip/hip_runtime.h>
#include <hip/hip_fp16.h>

// Problem constants (DirectedGraphLayer): B=2, N=50000, FIN=128, FOUT=64, E=800000
#define Bc   2
#define Nn   50000
#define FINc 128
#define FOUTc 64
#define Mtot (Bc * Nn)          // 100000 combined (b,n) rows
#define CCOMB 128               // combined feature cols: [W cols 0..63 | W_self cols 0..63]
#define GB 1563                 // gemm tiles: ceil(100000/64)
#define CAP 64                  // per-row edge capacity (P(Poisson16>64)~1e-17)

// two-pass binning parameters
#define NRNG   128              // rows per bucket
#define NBUCK  391              // ceil(50000/128)
#define ABLK   256              // bin_a blocks
#define RECCAP 3200             // per-block record capacity (E/ABLK=3125)
#define BCAP   2432             // per-bucket stage capacity (mean 2046, +8.5 sigma)

typedef __bf16 bf16x8 __attribute__((ext_vector_type(8)));
typedef float  f32x4  __attribute__((ext_vector_type(4)));

static __device__ inline unsigned short f2bf(float f) {
    unsigned int u = __float_as_uint(f);
    u += 0x7fffu + ((u >> 16) & 1u);       // round-to-nearest-even
    return (unsigned short)(u >> 16);
}

// ---------------------------------------------------------------------------
// prep: blocks 0..7 pack [W|W_self] -> fragment-major bf16 (MFMA A-operand
// layout); block 8 zeroes the per-bucket fill counters (cntp no longer needs
// zeroing: bin_b writes every row's count directly).
// ---------------------------------------------------------------------------
__global__ __launch_bounds__(256) void prep(
    const float* __restrict__ W, const float* __restrict__ Ws,
    unsigned short* __restrict__ Bp, unsigned int* __restrict__ bfill)
{
    if (blockIdx.x < 8) {
        const int idx = blockIdx.x * 256 + threadIdx.x;
        const int lane = idx & 63;
        const int kt   = (idx >> 6) & 3;
        const int nt   = idx >> 8;
        const int n    = nt * 16 + (lane & 15);
        const int k0   = kt * 32 + (lane >> 4) * 8;
        unsigned short o8[8];
#pragma unroll
        for (int j = 0; j < 8; ++j) {
            const int f = k0 + j;
            const float v = (n < 64) ? W[f * FOUTc + n] : Ws[f * FOUTc + (n - 64)];
            o8[j] = f2bf(v);
        }
        *(uint4*)&Bp[(size_t)idx * 8] = *(uint4*)o8;
    } else {
        for (int i = threadIdx.x; i < NBUCK; i += 256) bfill[i] = 0u;
    }
}

// ---------------------------------------------------------------------------
// gemm: one 64-row MFMA tile per block (A=weights fragment-major, B=x rows).
//   cols 0..63  -> xrb (bf16, (N, B*64) layout)
//   cols 64..127-> outp pre-ReLU self term (+bias, f32)
// ---------------------------------------------------------------------------
__global__ __launch_bounds__(256) void gemm(
    const float* __restrict__ x, const unsigned short* __restrict__ Bp,
    const float* __restrict__ bself,
    unsigned short* __restrict__ xrb, float* __restrict__ outp)
{
    const int gb   = blockIdx.x;             // 0..GB-1
    const int lane = threadIdx.x & 63;
    const int quad = lane >> 4;
    const int mbase = gb * 64 + (threadIdx.x >> 6) * 16;

    const int mrow   = mbase + (lane & 15);
    const int mclamp = (mrow < Mtot) ? mrow : (Mtot - 1);
    const float* __restrict__ xrow = &x[(size_t)mclamp * FINc + quad * 8];

    float4 xv[8];
#pragma unroll
    for (int kt = 0; kt < 4; ++kt) {
        xv[2 * kt]     = *(const float4*)&xrow[kt * 32];
        xv[2 * kt + 1] = *(const float4*)&xrow[kt * 32 + 4];
    }

    f32x4 acc[8] = {};

#pragma unroll
    for (int kt = 0; kt < 4; ++kt) {
        const float4 xa = xv[2 * kt];
        const float4 xb = xv[2 * kt + 1];
        bf16x8 bf;                       // B operand: B[k][m], m=lane&15
        bf[0] = (__bf16)xa.x; bf[1] = (__bf16)xa.y;
        bf[2] = (__bf16)xa.z; bf[3] = (__bf16)xa.w;
        bf[4] = (__bf16)xb.x; bf[5] = (__bf16)xb.y;
        bf[6] = (__bf16)xb.z; bf[7] = (__bf16)xb.w;

        const bf16x8* __restrict__ abase =
            (const bf16x8*)&Bp[(size_t)(kt * 64 + lane) * 8];
#pragma unroll
        for (int nt = 0; nt < 8; ++nt) {
            const bf16x8 af = abase[nt * 4 * 64];   // entry (nt*4+kt)*64+lane
            acc[nt] = __builtin_amdgcn_mfma_f32_16x16x32_bf16(af, bf, acc[nt], 0, 0, 0);
        }
    }

    const int m = mbase + (lane & 15);
    if (m < Mtot) {
        const int bb = (m >= Nn) ? 1 : 0;
        const int n = m - bb * Nn;
        unsigned short* __restrict__ xp = &xrb[(size_t)n * CCOMB + bb * FOUTc];
        const int cq = quad * 4;
#pragma unroll
        for (int nt = 0; nt < 4; ++nt) {
            const int c = nt * 16 + cq;
            unsigned short h[4];
            h[0] = f2bf(acc[nt][0]); h[1] = f2bf(acc[nt][1]);
            h[2] = f2bf(acc[nt][2]); h[3] = f2bf(acc[nt][3]);
            *(uint2*)&xp[c] = *(uint2*)h;           // 8 B store
        }
        float* __restrict__ op = &outp[(size_t)m * FOUTc];
#pragma unroll
        for (int nt = 4; nt < 8; ++nt) {
            const int o = (nt - 4) * 16 + cq;
            const float4 b4 = *(const float4*)&bself[o];
            float4 v;
            v.x = acc[nt][0] + b4.x; v.y = acc[nt][1] + b4.y;
            v.z = acc[nt][2] + b4.z; v.w = acc[nt][3] + b4.w;
            *(float4*)&op[o] = v;                   // 16 B store, line-dense
        }
    }
}

// ---------------------------------------------------------------------------
// bin_a: two-pass LDS binning of edges into per-row-range stage segments.
// Replaces 800K device-scope returning atomics + 800K random 4B stores with
// LDS atomics + ~100K range-reservation atomics + piecewise-coalesced 8B
// writes. Record = {valcol (same packing as cvp), (bucket<<7)|row_local}.
// ---------------------------------------------------------------------------
__global__ __launch_bounds__(256) void bin_a(
    const int* __restrict__ erow, const int* __restrict__ ecol,
    const float* __restrict__ evalv, unsigned int* __restrict__ bfill,
    uint2* __restrict__ stage, int E, int ec)
{
    __shared__ unsigned int hist[512];     // per-bucket counts (padded)
    __shared__ unsigned int incl[512];     // inclusive scan
    __shared__ unsigned int gbase[NBUCK];  // this block's global reservation
    __shared__ unsigned int cur[NBUCK];    // LDS write cursors
    __shared__ unsigned int recs[RECCAP * 2];

    const int tid = threadIdx.x;
    const int e0 = blockIdx.x * ec;
    int e1 = e0 + ec; if (e1 > E) e1 = E;
    if (e1 - e0 > RECCAP) e1 = e0 + RECCAP;   // safety (never hit at E=800000)
    const int tot = e1 - e0;

    hist[tid] = 0u; hist[tid + 256] = 0u;
    __syncthreads();

    // pass 1: histogram over row ranges
    for (int e = e0 + tid; e < e1; e += 256) {
        const int r = erow[e];
        atomicAdd(&hist[r >> 7], 1u);
    }
    __syncthreads();

    // inclusive Hillis-Steele scan over 512 entries
    incl[tid] = hist[tid]; incl[tid + 256] = hist[tid + 256];
    __syncthreads();
    for (int off = 1; off < 512; off <<= 1) {
        const unsigned int a0 = (tid >= off) ? incl[tid - off] : 0u;
        const unsigned int a1 = ((tid + 256) >= off) ? incl[tid + 256 - off] : 0u;
        __syncthreads();
        incl[tid] += a0; incl[tid + 256] += a1;
        __syncthreads();
    }

    // reserve global stage ranges; init LDS cursors to exclusive offsets
    for (int i = tid; i < NBUCK; i += 256) {
        const unsigned int c = hist[i];
        cur[i]   = incl[i] - c;
        gbase[i] = c ? atomicAdd(&bfill[i], c) : 0u;
    }
    __syncthreads();

    // pass 2: re-read edges, group records by bucket in LDS
    for (int e = e0 + tid; e < e1; e += 256) {
        const int   r = erow[e];
        const int   c = ecol[e];
        const float v = evalv[e];
        const int  nb = r >> 7;
        const unsigned int k = atomicAdd(&cur[nb], 1u);
        recs[2 * k]     = ((unsigned int)__half_as_ushort(__float2half(v)) << 17) |
                          (unsigned int)c;
        recs[2 * k + 1] = ((unsigned int)nb << 7) | (unsigned int)(r & 127);
    }
    __syncthreads();

    // pass 3: stream grouped records to global stage (piecewise contiguous)
    for (int j = tid; j < tot; j += 256) {
        const unsigned int vc   = recs[2 * j];
        const unsigned int meta = recs[2 * j + 1];
        const int nb = (int)(meta >> 7);
        const unsigned int excl = incl[nb] - hist[nb];
        const unsigned int slot = gbase[nb] + ((unsigned int)j - excl);
        if (slot < BCAP)
            stage[(size_t)nb * BCAP + slot] = make_uint2(vc, meta);
    }
}

// ---------------------------------------------------------------------------
// bin_b: one block per bucket. Reads its contiguous stage segment, bins into
// per-row CAP-64 lists entirely in LDS, streams cvp + cntp out coalesced.
// ---------------------------------------------------------------------------
__global__ __launch_bounds__(256) void bin_b(
    const unsigned int* __restrict__ bfill, const uint2* __restrict__ stage,
    unsigned int* __restrict__ cvp, int* __restrict__ cntp)
{
    __shared__ unsigned int lists[NRNG * CAP];   // 32 KB
    __shared__ unsigned int lcnt[NRNG];

    const int tid = threadIdx.x;
    const int nb  = blockIdx.x;
    const int row0 = nb << 7;
    int nrows = Nn - row0; if (nrows > NRNG) nrows = NRNG;

    for (int i = tid; i < NRNG; i += 256) lcnt[i] = 0u;
    __syncthreads();

    unsigned int cnt = bfill[nb];
    if (cnt > BCAP) cnt = BCAP;
    const uint2* __restrict__ seg = &stage[(size_t)nb * BCAP];

    for (unsigned int j = tid; j < cnt; j += 256) {
        const uint2 rec = seg[j];
        const int rl = (int)(rec.y & 127u);
        const unsigned int k = atomicAdd(&lcnt[rl], 1u);
        if (k < CAP) lists[(rl << 6) + k] = rec.x;
    }
    __syncthreads();

    // coalesced stream-out (garbage slots beyond count are masked by gather)
    unsigned int* __restrict__ dst = &cvp[(size_t)row0 << 6];
    const int words = nrows << 6;
    for (int i = tid; i < words; i += 256) dst[i] = lists[i];
    for (int rl = tid; rl < nrows; rl += 256) {
        const unsigned int c = lcnt[rl];
        cntp[(size_t)(row0 + rl) * 16] = (int)(c < CAP ? c : CAP);
    }
}

// ---------------------------------------------------------------------------
// row_gather: XCD-affine half-row jobs. Fixed-CAP (64, line-aligned) layout:
// first 16 edge words (one 64 B line) have KNOWN addresses -> cvp[slot],
// cvp[8+slot], count all load in parallel; gather xrb speculatively; zero
// multiplier for slots >= count. Fused finalize: out = relu(self_pre + agg).
// ---------------------------------------------------------------------------
#define GATHP(W, PRED, ACC)                                                   \
    {                                                                         \
        const unsigned int w = (W);                                           \
        unsigned int col = w & 0x1FFFFu;                                      \
        col = (col < Nn) ? col : 0u;       /* clamp speculative garbage */    \
        const float vv = (PRED) ? __half2float(__ushort_as_half(              \
                             (unsigned short)(w >> 17))) : 0.0f;              \
        const uint4 raw = *(const uint4*)&xrb[(size_t)col * CCOMB + c0];      \
        ACC[0] = fmaf(vv, __uint_as_float(raw.x << 16),         ACC[0]);      \
        ACC[1] = fmaf(vv, __uint_as_float(raw.x & 0xffff0000u), ACC[1]);      \
        ACC[2] = fmaf(vv, __uint_as_float(raw.y << 16),         ACC[2]);      \
        ACC[3] = fmaf(vv, __uint_as_float(raw.y & 0xffff0000u), ACC[3]);      \
        ACC[4] = fmaf(vv, __uint_as_float(raw.z << 16),         ACC[4]);      \
        ACC[5] = fmaf(vv, __uint_as_float(raw.z & 0xffff0000u), ACC[5]);      \
        ACC[6] = fmaf(vv, __uint_as_float(raw.w << 16),         ACC[6]);      \
        ACC[7] = fmaf(vv, __uint_as_float(raw.w & 0xffff0000u), ACC[7]);      \
    }

__global__ __launch_bounds__(256) void row_gather(
    const int* __restrict__ cntp, const unsigned int* __restrict__ cvp,
    const unsigned short* __restrict__ xrb, float* __restrict__ outp)
{
    const int j    = blockIdx.x;
    const int low3 = j & 7;
    const int h    = (low3 >= 4) ? 1 : 0;      // batch half -> XCD group
    const int ord  = (j >> 3) * 4 + (low3 & 3);
    int n = ord * 4 + (threadIdx.x >> 6);
    n = __builtin_amdgcn_readfirstlane(n);     // wave-uniform -> scalar loads

    const int lane = threadIdx.x & 63;
    const int slot = lane >> 3;                // edge slot 0..7
    const int c0   = h * 64 + (lane & 7) * 8;  // 8 combined cols per lane
    const unsigned int* __restrict__ seg = &cvp[(size_t)n << 6];

    // three independent loads issue together
    const int kc = min(cntp[(size_t)n * 16], CAP);
    const unsigned int u0 = seg[slot];
    const unsigned int u1 = seg[8 + slot];

    float aA[8] = {0.f, 0.f, 0.f, 0.f, 0.f, 0.f, 0.f, 0.f};

    GATHP(u0, slot < kc,     aA);
    GATHP(u1, slot + 8 < kc, aA);

    for (int e = 16 + slot; e < kc; e += 8) {
        const unsigned int u = seg[e];
        GATHP(u, true, aA);
    }

#pragma unroll
    for (int i = 0; i < 8; ++i) {
        aA[i] += __shfl_down(aA[i], 8);
        aA[i] += __shfl_down(aA[i], 16);
        aA[i] += __shfl_down(aA[i], 32);
    }

    if (lane < 8) {
        const size_t m = (size_t)h * Nn + n;
        const int o = lane * 8;                // feature offset within 64
        float* __restrict__ op = &outp[m * FOUTc + o];
        float4 s0 = *(float4*)&op[0];
        float4 s1 = *(float4*)&op[4];
        s0.x = fmaxf(s0.x + aA[0], 0.0f); s0.y = fmaxf(s0.y + aA[1], 0.0f);
        s0.z = fmaxf(s0.z + aA[2], 0.0f); s0.w = fmaxf(s0.w + aA[3], 0.0f);
        s1.x = fmaxf(s1.x + aA[4], 0.0f); s1.y = fmaxf(s1.y + aA[5], 0.0f);
        s1.z = fmaxf(s1.z + aA[6], 0.0f); s1.w = fmaxf(s1.w + aA[7], 0.0f);
        *(float4*)&op[0] = s0;
        *(float4*)&op[4] = s1;
    }
}

extern "C" void kernel_launch(void* const* d_in, const int* in_sizes, int n_in,
                              void* d_out, int out_size, void* d_ws, size_t ws_size,
                              hipStream_t stream)
{
    const float* x    = (const float*)d_in[0];
    const float* W    = (const float*)d_in[1];
    const float* Ws   = (const float*)d_in[2];
    const float* bs   = (const float*)d_in[3];
    const int*   erow = (const int*)d_in[4];
    const int*   ecol = (const int*)d_in[5];
    const float* eval = (const float*)d_in[6];
    float* outp = (float*)d_out;
    const int E = in_sizes[4];

    // workspace layout (~36.5 MB total; all bases 256 B aligned by construction)
    unsigned short* xrb = (unsigned short*)d_ws;                      // 12.8 MB
    unsigned int*   cvp = (unsigned int*)(xrb + (size_t)Nn * CCOMB);  // 12.8 MB
    int*            cntp = (int*)(cvp + ((size_t)Nn << 6));           // 3.2 MB
    unsigned short* Bp  = (unsigned short*)(cntp + (size_t)Nn * 16);  // 32 KB
    unsigned int*   bfill = (unsigned int*)(Bp + 16384);              // 2 KB (512 u32)
    uint2*          stage = (uint2*)(bfill + 512);                    // 7.6 MB

    const int ec = (E + ABLK - 1) / ABLK;

    // 1. pack weights + zero bucket fills
    prep<<<9, 256, 0, stream>>>(W, Ws, Bp, bfill);

    // 2. dense transform + self term (MFMA)
    gemm<<<GB, 256, 0, stream>>>(x, Bp, bs, xrb, outp);

    // 3. two-pass binning (replaces per-edge device atomics)
    bin_a<<<ABLK, 256, 0, stream>>>(erow, ecol, eval, bfill, stage, E, ec);
    bin_b<<<NBUCK, 256, 0, stream>>>(bfill, stage, cvp, cntp);

    // 4. per-half-row speculative gather-reduce fused with finalize
    row_gather<<<Nn / 2, 256, 0, stream>>>(cntp, cvp, xrb, outp);
}

// Round 4
// 179.140 us; speedup vs baseline: 1.1251x; 1.0342x over previous
//
#include <hip/hip_runtime.h>
#include <hip/hip_fp16.h>

// Problem constants (DirectedGraphLayer): B=2, N=50000, FIN=128, FOUT=64, E=800000
#define Bc   2
#define Nn   50000
#define FINc 128
#define FOUTc 64
#define Mtot (Bc * Nn)          // 100000 combined (b,n) rows
#define CCOMB 128               // combined feature cols: [W cols 0..63 | W_self cols 0..63]
#define GB 1563                 // gemm tiles: ceil(100000/64)
#define CAP 64                  // per-row edge capacity (P(Poisson16>64)~1e-17)

// binning parameters
#define NRNG   128              // rows per bucket
#define NBUCK  391              // ceil(50000/128)
#define ABLK   256              // bin_a role blocks
#define BCAP   2432             // per-bucket stage capacity (mean 2046, +8.5 sigma)
#define FUSED_GRID (ABLK * 9)   // 2304: 1 bin_a per 9 blocks (rotates across XCDs)

typedef __bf16 bf16x8 __attribute__((ext_vector_type(8)));
typedef float  f32x4  __attribute__((ext_vector_type(4)));

static __device__ inline unsigned short f2bf(float f) {
    unsigned int u = __float_as_uint(f);
    u += 0x7fffu + ((u >> 16) & 1u);       // round-to-nearest-even
    return (unsigned short)(u >> 16);
}

// ---------------------------------------------------------------------------
// prep: blocks 0..7 pack [W|W_self] -> fragment-major bf16 (MFMA A-operand
// layout); block 8 zeroes the per-bucket fill counters.
// ---------------------------------------------------------------------------
__global__ __launch_bounds__(256) void prep(
    const float* __restrict__ W, const float* __restrict__ Ws,
    unsigned short* __restrict__ Bp, unsigned int* __restrict__ bfill)
{
    if (blockIdx.x < 8) {
        const int idx = blockIdx.x * 256 + threadIdx.x;
        const int lane = idx & 63;
        const int kt   = (idx >> 6) & 3;
        const int nt   = idx >> 8;
        const int n    = nt * 16 + (lane & 15);
        const int k0   = kt * 32 + (lane >> 4) * 8;
        unsigned short o8[8];
#pragma unroll
        for (int j = 0; j < 8; ++j) {
            const int f = k0 + j;
            const float v = (n < 64) ? W[f * FOUTc + n] : Ws[f * FOUTc + (n - 64)];
            o8[j] = f2bf(v);
        }
        *(uint4*)&Bp[(size_t)idx * 8] = *(uint4*)o8;
    } else {
        for (int i = threadIdx.x; i < NBUCK; i += 256) bfill[i] = 0u;
    }
}

// ---------------------------------------------------------------------------
// gemm_bina: fused independent roles, resource-complementary overlap.
//   blocks with b%9==8 (rotating XCD): bin_a — LDS histogram over row
//     buckets, one reservation atomic per non-empty bucket (~100K total vs
//     800K per-edge), then direct 8 B stores into per-bucket stage segments
//     (block-local runs are contiguous -> L2 merges lines).
//   other blocks: one 64-row MFMA gemm tile (A=weights, B=x rows).
//     cols 0..63  -> xrb (bf16, (N, B*64) layout)
//     cols 64..127-> outp pre-ReLU self term (+bias, f32)
// bin_a is latency-bound with tiny BW; gemm is BW/MFMA-bound -> overlap
// hides bin_a. LDS ~5 KB so gemm occupancy is wave-limited, not LDS-limited.
// ---------------------------------------------------------------------------
__global__ __launch_bounds__(256) void gemm_bina(
    const float* __restrict__ x, const unsigned short* __restrict__ Bp,
    const float* __restrict__ bself,
    unsigned short* __restrict__ xrb, float* __restrict__ outp,
    const int* __restrict__ erow, const int* __restrict__ ecol,
    const float* __restrict__ evalv, unsigned int* __restrict__ bfill,
    uint2* __restrict__ stage, int E, int ec)
{
    const int b  = blockIdx.x;
    const int r9 = b % 9;

    if (r9 == 8) {
        // ---- bin_a role ----
        __shared__ unsigned int hist[512];
        __shared__ unsigned int gbase[NBUCK];
        __shared__ unsigned int cur[NBUCK];

        const int tid = threadIdx.x;
        const int ord = b / 9;                 // 0..ABLK-1
        const int e0 = ord * ec;
        int e1 = e0 + ec; if (e1 > E) e1 = E;

        hist[tid] = 0u; hist[tid + 256] = 0u;
        for (int i = tid; i < NBUCK; i += 256) cur[i] = 0u;
        __syncthreads();

        // pass 1: histogram over row buckets
        for (int e = e0 + tid; e < e1; e += 256)
            atomicAdd(&hist[erow[e] >> 7], 1u);
        __syncthreads();

        // reserve global stage ranges (one atomic per non-empty bucket)
        for (int i = tid; i < NBUCK; i += 256) {
            const unsigned int c = hist[i];
            gbase[i] = c ? atomicAdd(&bfill[i], c) : 0u;
        }
        __syncthreads();

        // pass 2: direct stores into reserved slots (bucket-contiguous runs)
        for (int e = e0 + tid; e < e1; e += 256) {
            const int   r = erow[e];
            const int   c = ecol[e];
            const float v = evalv[e];
            const int  nb = r >> 7;
            const unsigned int k = gbase[nb] + atomicAdd(&cur[nb], 1u);
            if (k < BCAP)
                stage[(size_t)nb * BCAP + k] = make_uint2(
                    ((unsigned int)__half_as_ushort(__float2half(v)) << 17) |
                        (unsigned int)c,
                    (unsigned int)(r & 127));
        }
        return;
    }

    // ---- gemm role ----
    const int gb = b - (b + 1) / 9;          // ordinal among non-bin_a blocks
    if (gb >= GB) return;
    const int lane = threadIdx.x & 63;
    const int quad = lane >> 4;
    const int mbase = gb * 64 + (threadIdx.x >> 6) * 16;

    const int mrow   = mbase + (lane & 15);
    const int mclamp = (mrow < Mtot) ? mrow : (Mtot - 1);
    const float* __restrict__ xrow = &x[(size_t)mclamp * FINc + quad * 8];

    float4 xv[8];
#pragma unroll
    for (int kt = 0; kt < 4; ++kt) {
        xv[2 * kt]     = *(const float4*)&xrow[kt * 32];
        xv[2 * kt + 1] = *(const float4*)&xrow[kt * 32 + 4];
    }

    f32x4 acc[8] = {};

#pragma unroll
    for (int kt = 0; kt < 4; ++kt) {
        const float4 xa = xv[2 * kt];
        const float4 xb = xv[2 * kt + 1];
        bf16x8 bf;                       // B operand: B[k][m], m=lane&15
        bf[0] = (__bf16)xa.x; bf[1] = (__bf16)xa.y;
        bf[2] = (__bf16)xa.z; bf[3] = (__bf16)xa.w;
        bf[4] = (__bf16)xb.x; bf[5] = (__bf16)xb.y;
        bf[6] = (__bf16)xb.z; bf[7] = (__bf16)xb.w;

        const bf16x8* __restrict__ abase =
            (const bf16x8*)&Bp[(size_t)(kt * 64 + lane) * 8];
#pragma unroll
        for (int nt = 0; nt < 8; ++nt) {
            const bf16x8 af = abase[nt * 4 * 64];   // entry (nt*4+kt)*64+lane
            acc[nt] = __builtin_amdgcn_mfma_f32_16x16x32_bf16(af, bf, acc[nt], 0, 0, 0);
        }
    }

    const int m = mbase + (lane & 15);
    if (m < Mtot) {
        const int bb = (m >= Nn) ? 1 : 0;
        const int n = m - bb * Nn;
        unsigned short* __restrict__ xp = &xrb[(size_t)n * CCOMB + bb * FOUTc];
        const int cq = quad * 4;
#pragma unroll
        for (int nt = 0; nt < 4; ++nt) {
            const int c = nt * 16 + cq;
            unsigned short h[4];
            h[0] = f2bf(acc[nt][0]); h[1] = f2bf(acc[nt][1]);
            h[2] = f2bf(acc[nt][2]); h[3] = f2bf(acc[nt][3]);
            *(uint2*)&xp[c] = *(uint2*)h;           // 8 B store
        }
        float* __restrict__ op = &outp[(size_t)m * FOUTc];
#pragma unroll
        for (int nt = 4; nt < 8; ++nt) {
            const int o = (nt - 4) * 16 + cq;
            const float4 b4 = *(const float4*)&bself[o];
            float4 v;
            v.x = acc[nt][0] + b4.x; v.y = acc[nt][1] + b4.y;
            v.z = acc[nt][2] + b4.z; v.w = acc[nt][3] + b4.w;
            *(float4*)&op[o] = v;                   // 16 B store, line-dense
        }
    }
}

// ---------------------------------------------------------------------------
// bin_b: one block per bucket. Reads its contiguous stage segment, bins into
// per-row CAP-64 lists entirely in LDS, streams cvp + cntp out coalesced.
// ---------------------------------------------------------------------------
__global__ __launch_bounds__(256) void bin_b(
    const unsigned int* __restrict__ bfill, const uint2* __restrict__ stage,
    unsigned int* __restrict__ cvp, int* __restrict__ cntp)
{
    __shared__ unsigned int lists[NRNG * CAP];   // 32 KB
    __shared__ unsigned int lcnt[NRNG];

    const int tid = threadIdx.x;
    const int nb  = blockIdx.x;
    const int row0 = nb << 7;
    int nrows = Nn - row0; if (nrows > NRNG) nrows = NRNG;

    for (int i = tid; i < NRNG; i += 256) lcnt[i] = 0u;
    __syncthreads();

    unsigned int cnt = bfill[nb];
    if (cnt > BCAP) cnt = BCAP;
    const uint2* __restrict__ seg = &stage[(size_t)nb * BCAP];

    for (unsigned int j = tid; j < cnt; j += 256) {
        const uint2 rec = seg[j];
        const int rl = (int)(rec.y & 127u);
        const unsigned int k = atomicAdd(&lcnt[rl], 1u);
        if (k < CAP) lists[(rl << 6) + k] = rec.x;
    }
    __syncthreads();

    // coalesced stream-out (garbage slots beyond count are masked by gather)
    unsigned int* __restrict__ dst = &cvp[(size_t)row0 << 6];
    const int words = nrows << 6;
    for (int i = tid; i < words; i += 256) dst[i] = lists[i];
    for (int rl = tid; rl < nrows; rl += 256) {
        const unsigned int c = lcnt[rl];
        cntp[(size_t)(row0 + rl) * 16] = (int)(c < CAP ? c : CAP);
    }
}

// ---------------------------------------------------------------------------
// row_gather: XCD-affine half-row jobs. Fixed-CAP (64, line-aligned) layout:
// first 16 edge words (one 64 B line) have KNOWN addresses -> cvp[slot],
// cvp[8+slot], count all load in parallel; gather xrb speculatively; zero
// multiplier for slots >= count. Fused finalize: out = relu(self_pre + agg).
// ---------------------------------------------------------------------------
#define GATHP(W, PRED, ACC)                                                   \
    {                                                                         \
        const unsigned int w = (W);                                           \
        unsigned int col = w & 0x1FFFFu;                                      \
        col = (col < Nn) ? col : 0u;       /* clamp speculative garbage */    \
        const float vv = (PRED) ? __half2float(__ushort_as_half(              \
                             (unsigned short)(w >> 17))) : 0.0f;              \
        const uint4 raw = *(const uint4*)&xrb[(size_t)col * CCOMB + c0];      \
        ACC[0] = fmaf(vv, __uint_as_float(raw.x << 16),         ACC[0]);      \
        ACC[1] = fmaf(vv, __uint_as_float(raw.x & 0xffff0000u), ACC[1]);      \
        ACC[2] = fmaf(vv, __uint_as_float(raw.y << 16),         ACC[2]);      \
        ACC[3] = fmaf(vv, __uint_as_float(raw.y & 0xffff0000u), ACC[3]);      \
        ACC[4] = fmaf(vv, __uint_as_float(raw.z << 16),         ACC[4]);      \
        ACC[5] = fmaf(vv, __uint_as_float(raw.z & 0xffff0000u), ACC[5]);      \
        ACC[6] = fmaf(vv, __uint_as_float(raw.w << 16),         ACC[6]);      \
        ACC[7] = fmaf(vv, __uint_as_float(raw.w & 0xffff0000u), ACC[7]);      \
    }

__global__ __launch_bounds__(256) void row_gather(
    const int* __restrict__ cntp, const unsigned int* __restrict__ cvp,
    const unsigned short* __restrict__ xrb, float* __restrict__ outp)
{
    const int j    = blockIdx.x;
    const int low3 = j & 7;
    const int h    = (low3 >= 4) ? 1 : 0;      // batch half -> XCD group
    const int ord  = (j >> 3) * 4 + (low3 & 3);
    int n = ord * 4 + (threadIdx.x >> 6);
    n = __builtin_amdgcn_readfirstlane(n);     // wave-uniform -> scalar loads

    const int lane = threadIdx.x & 63;
    const int slot = lane >> 3;                // edge slot 0..7
    const int c0   = h * 64 + (lane & 7) * 8;  // 8 combined cols per lane
    const unsigned int* __restrict__ seg = &cvp[(size_t)n << 6];

    // three independent loads issue together
    const int kc = min(cntp[(size_t)n * 16], CAP);
    const unsigned int u0 = seg[slot];
    const unsigned int u1 = seg[8 + slot];

    float aA[8] = {0.f, 0.f, 0.f, 0.f, 0.f, 0.f, 0.f, 0.f};

    GATHP(u0, slot < kc,     aA);
    GATHP(u1, slot + 8 < kc, aA);

    for (int e = 16 + slot; e < kc; e += 8) {
        const unsigned int u = seg[e];
        GATHP(u, true, aA);
    }

#pragma unroll
    for (int i = 0; i < 8; ++i) {
        aA[i] += __shfl_down(aA[i], 8);
        aA[i] += __shfl_down(aA[i], 16);
        aA[i] += __shfl_down(aA[i], 32);
    }

    if (lane < 8) {
        const size_t m = (size_t)h * Nn + n;
        const int o = lane * 8;                // feature offset within 64
        float* __restrict__ op = &outp[m * FOUTc + o];
        float4 s0 = *(float4*)&op[0];
        float4 s1 = *(float4*)&op[4];
        s0.x = fmaxf(s0.x + aA[0], 0.0f); s0.y = fmaxf(s0.y + aA[1], 0.0f);
        s0.z = fmaxf(s0.z + aA[2], 0.0f); s0.w = fmaxf(s0.w + aA[3], 0.0f);
        s1.x = fmaxf(s1.x + aA[4], 0.0f); s1.y = fmaxf(s1.y + aA[5], 0.0f);
        s1.z = fmaxf(s1.z + aA[6], 0.0f); s1.w = fmaxf(s1.w + aA[7], 0.0f);
        *(float4*)&op[0] = s0;
        *(float4*)&op[4] = s1;
    }
}

extern "C" void kernel_launch(void* const* d_in, const int* in_sizes, int n_in,
                              void* d_out, int out_size, void* d_ws, size_t ws_size,
                              hipStream_t stream)
{
    const float* x    = (const float*)d_in[0];
    const float* W    = (const float*)d_in[1];
    const float* Ws   = (const float*)d_in[2];
    const float* bs   = (const float*)d_in[3];
    const int*   erow = (const int*)d_in[4];
    const int*   ecol = (const int*)d_in[5];
    const float* eval = (const float*)d_in[6];
    float* outp = (float*)d_out;
    const int E = in_sizes[4];

    // workspace layout (~36.5 MB total; all bases 256 B aligned by construction)
    unsigned short* xrb = (unsigned short*)d_ws;                      // 12.8 MB
    unsigned int*   cvp = (unsigned int*)(xrb + (size_t)Nn * CCOMB);  // 12.8 MB
    int*            cntp = (int*)(cvp + ((size_t)Nn << 6));           // 3.2 MB
    unsigned short* Bp  = (unsigned short*)(cntp + (size_t)Nn * 16);  // 32 KB
    unsigned int*   bfill = (unsigned int*)(Bp + 16384);              // 2 KB (512 u32)
    uint2*          stage = (uint2*)(bfill + 512);                    // 7.6 MB

    const int ec = (E + ABLK - 1) / ABLK;

    // 1. pack weights + zero bucket fills
    prep<<<9, 256, 0, stream>>>(W, Ws, Bp, bfill);

    // 2. fused: dense MFMA transform + edge binning pass A (overlapped roles)
    gemm_bina<<<FUSED_GRID, 256, 0, stream>>>(x, Bp, bs, xrb, outp,
                                              erow, ecol, eval, bfill,
                                              stage, E, ec);

    // 3. bucket -> per-row CAP lists, coalesced cvp/cntp stream-out
    bin_b<<<NBUCK, 256, 0, stream>>>(bfill, stage, cvp, cntp);

    // 4. per-half-row speculative gather-reduce fused with finalize
    row_gather<<<Nn / 2, 256, 0, stream>>>(cntp, cvp, xrb, outp);
}

// Round 6
// 178.448 us; speedup vs baseline: 1.1295x; 1.0039x over previous
//
#include <hip/hip_runtime.h>
#include <hip/hip_fp16.h>

// Problem constants (DirectedGraphLayer): B=2, N=50000, FIN=128, FOUT=64, E=800000
#define Bc   2
#define Nn   50000
#define FINc 128
#define FOUTc 64
#define Mtot (Bc * Nn)          // 100000 combined (b,n) rows
#define CCOMB 128               // combined feature cols: [W cols 0..63 | W_self cols 0..63]
#define GB 1563                 // gemm tiles: ceil(100000/64)
#define CAP 64                  // per-row edge capacity (P(Poisson16>64)~1e-17)

// binning parameters
#define NRNG   128              // rows per bucket
#define NBUCK  391              // ceil(50000/128)
#define ABLK   256              // bin_a role blocks
#define RECCAP 3200             // per-block stage chunk capacity (E/ABLK=3125)
#define FUSED_GRID (ABLK * 9)   // 2304: 1 bin_a per 9 blocks (rotates across XCDs)

typedef __bf16 bf16x8 __attribute__((ext_vector_type(8)));
typedef float  f32x4  __attribute__((ext_vector_type(4)));

static __device__ inline unsigned short f2bf(float f) {
    unsigned int u = __float_as_uint(f);
    u += 0x7fffu + ((u >> 16) & 1u);       // round-to-nearest-even
    return (unsigned short)(u >> 16);
}

// ---------------------------------------------------------------------------
// prep: 8 blocks pack [W|W_self] -> fragment-major bf16 (MFMA A-operand
// layout). No counters to zero anymore (bin path is atomic-free).
// ---------------------------------------------------------------------------
__global__ __launch_bounds__(256) void prep(
    const float* __restrict__ W, const float* __restrict__ Ws,
    unsigned short* __restrict__ Bp)
{
    const int idx = blockIdx.x * 256 + threadIdx.x;
    const int lane = idx & 63;
    const int kt   = (idx >> 6) & 3;
    const int nt   = idx >> 8;
    const int n    = nt * 16 + (lane & 15);
    const int k0   = kt * 32 + (lane >> 4) * 8;
    unsigned short o8[8];
#pragma unroll
    for (int j = 0; j < 8; ++j) {
        const int f = k0 + j;
        const float v = (n < 64) ? W[f * FOUTc + n] : Ws[f * FOUTc + (n - 64)];
        o8[j] = f2bf(v);
    }
    *(uint4*)&Bp[(size_t)idx * 8] = *(uint4*)o8;
}

// ---------------------------------------------------------------------------
// gemm_bina: fused independent roles.
//   blocks with b%9==8: bin_a — ATOMIC-FREE radix pass. LDS histogram over
//     391 row-buckets + LDS scan; records regrouped by bucket in LDS; then
//     (1) contiguous coalesced dump into this block's PRIVATE stage chunk,
//     (2) per-(block,bucket) cnt/ofs rows written coalesced.
//     R4's version had 256-deep same-address device-atomic chains on the
//     bucket reservation words (~35 us of serialized RMW) plus random 8 B
//     stage stores (RFO + full-line writeback). Both eliminated.
//   other blocks: one 64-row MFMA gemm tile (A=weights, B=x rows).
//     cols 0..63  -> xrb (bf16, (N, B*64) layout)
//     cols 64..127-> outp pre-ReLU self term (+bias, f32)
// ---------------------------------------------------------------------------
__global__ __launch_bounds__(256) void gemm_bina(
    const float* __restrict__ x, const unsigned short* __restrict__ Bp,
    const float* __restrict__ bself,
    unsigned short* __restrict__ xrb, float* __restrict__ outp,
    const int* __restrict__ erow, const int* __restrict__ ecol,
    const float* __restrict__ evalv, unsigned int* __restrict__ cntm,
    unsigned int* __restrict__ ofsm, uint2* __restrict__ stage,
    int E, int ec)
{
    const int b  = blockIdx.x;
    const int r9 = b % 9;

    if (r9 == 8) {
        // ---- bin_a role (atomic-free) ----
        __shared__ unsigned int hist[512];
        __shared__ unsigned int incl[512];
        __shared__ unsigned int cur[NBUCK];
        __shared__ unsigned int recs[RECCAP * 2];

        const int tid = threadIdx.x;
        const int ord = b / 9;                 // 0..ABLK-1
        const int e0 = ord * ec;
        int e1 = e0 + ec; if (e1 > E) e1 = E;
        if (e1 - e0 > RECCAP) e1 = e0 + RECCAP;  // safety clamp
        const int tot = e1 - e0;

        hist[tid] = 0u; hist[tid + 256] = 0u;
        __syncthreads();

        // pass 1: histogram over row buckets
        for (int e = e0 + tid; e < e1; e += 256)
            atomicAdd(&hist[erow[e] >> 7], 1u);
        __syncthreads();

        // inclusive Hillis-Steele scan over 512 entries
        incl[tid] = hist[tid]; incl[tid + 256] = hist[tid + 256];
        __syncthreads();
        for (int off = 1; off < 512; off <<= 1) {
            const unsigned int a0 = (tid >= off) ? incl[tid - off] : 0u;
            const unsigned int a1 = ((tid + 256) >= off) ? incl[tid + 256 - off] : 0u;
            __syncthreads();
            incl[tid] += a0; incl[tid + 256] += a1;
            __syncthreads();
        }

        // init LDS cursors to exclusive offsets; emit cnt/ofs rows (coalesced)
        for (int i = tid; i < NBUCK; i += 256) {
            const unsigned int c = hist[i];
            const unsigned int x0 = incl[i] - c;
            cur[i] = x0;
            cntm[(size_t)ord * NBUCK + i] = c;
            ofsm[(size_t)ord * NBUCK + i] = x0;
        }
        __syncthreads();

        // pass 2: re-read edges, regroup records by bucket in LDS
        for (int e = e0 + tid; e < e1; e += 256) {
            const int   r = erow[e];
            const int   c = ecol[e];
            const float v = evalv[e];
            const int  nb = r >> 7;
            const unsigned int k = atomicAdd(&cur[nb], 1u);
            recs[2 * k]     = ((unsigned int)__half_as_ushort(__float2half(v)) << 17) |
                              (unsigned int)c;
            recs[2 * k + 1] = (unsigned int)(r & 127);
        }
        __syncthreads();

        // pass 3: contiguous coalesced dump into private stage chunk
        uint2* __restrict__ chunk = &stage[(size_t)ord * RECCAP];
        for (int j = tid; j < tot; j += 256)
            chunk[j] = make_uint2(recs[2 * j], recs[2 * j + 1]);
        return;
    }

    // ---- gemm role ----
    const int gb = b - (b + 1) / 9;          // ordinal among non-bin_a blocks
    if (gb >= GB) return;
    const int lane = threadIdx.x & 63;
    const int quad = lane >> 4;
    const int mbase = gb * 64 + (threadIdx.x >> 6) * 16;

    const int mrow   = mbase + (lane & 15);
    const int mclamp = (mrow < Mtot) ? mrow : (Mtot - 1);
    const float* __restrict__ xrow = &x[(size_t)mclamp * FINc + quad * 8];

    float4 xv[8];
#pragma unroll
    for (int kt = 0; kt < 4; ++kt) {
        xv[2 * kt]     = *(const float4*)&xrow[kt * 32];
        xv[2 * kt + 1] = *(const float4*)&xrow[kt * 32 + 4];
    }

    f32x4 acc[8] = {};

#pragma unroll
    for (int kt = 0; kt < 4; ++kt) {
        const float4 xa = xv[2 * kt];
        const float4 xb = xv[2 * kt + 1];
        bf16x8 bf;                       // B operand: B[k][m], m=lane&15
        bf[0] = (__bf16)xa.x; bf[1] = (__bf16)xa.y;
        bf[2] = (__bf16)xa.z; bf[3] = (__bf16)xa.w;
        bf[4] = (__bf16)xb.x; bf[5] = (__bf16)xb.y;
        bf[6] = (__bf16)xb.z; bf[7] = (__bf16)xb.w;

        const bf16x8* __restrict__ abase =
            (const bf16x8*)&Bp[(size_t)(kt * 64 + lane) * 8];
#pragma unroll
        for (int nt = 0; nt < 8; ++nt) {
            const bf16x8 af = abase[nt * 4 * 64];   // entry (nt*4+kt)*64+lane
            acc[nt] = __builtin_amdgcn_mfma_f32_16x16x32_bf16(af, bf, acc[nt], 0, 0, 0);
        }
    }

    const int m = mbase + (lane & 15);
    if (m < Mtot) {
        const int bb = (m >= Nn) ? 1 : 0;
        const int n = m - bb * Nn;
        unsigned short* __restrict__ xp = &xrb[(size_t)n * CCOMB + bb * FOUTc];
        const int cq = quad * 4;
#pragma unroll
        for (int nt = 0; nt < 4; ++nt) {
            const int c = nt * 16 + cq;
            unsigned short h[4];
            h[0] = f2bf(acc[nt][0]); h[1] = f2bf(acc[nt][1]);
            h[2] = f2bf(acc[nt][2]); h[3] = f2bf(acc[nt][3]);
            *(uint2*)&xp[c] = *(uint2*)h;           // 8 B store
        }
        float* __restrict__ op = &outp[(size_t)m * FOUTc];
#pragma unroll
        for (int nt = 4; nt < 8; ++nt) {
            const int o = (nt - 4) * 16 + cq;
            const float4 b4 = *(const float4*)&bself[o];
            float4 v;
            v.x = acc[nt][0] + b4.x; v.y = acc[nt][1] + b4.y;
            v.z = acc[nt][2] + b4.z; v.w = acc[nt][3] + b4.w;
            *(float4*)&op[o] = v;                   // 16 B store, line-dense
        }
    }
}

// ---------------------------------------------------------------------------
// bin_b: one block per bucket. Thread t pulls block t's record run for this
// bucket (cnt/ofs matrix lookup -> ~8-record contiguous read from block t's
// private chunk), bins into per-row CAP-64 lists in LDS, streams cvp + cntp
// out coalesced. No device atomics anywhere.
// ---------------------------------------------------------------------------
__global__ __launch_bounds__(256) void bin_b(
    const unsigned int* __restrict__ cntm, const unsigned int* __restrict__ ofsm,
    const uint2* __restrict__ stage,
    unsigned int* __restrict__ cvp, int* __restrict__ cntp)
{
    __shared__ unsigned int lists[NRNG * CAP];   // 32 KB
    __shared__ unsigned int lcnt[NRNG];

    const int tid = threadIdx.x;
    const int nb  = blockIdx.x;
    const int row0 = nb << 7;
    int nrows = Nn - row0; if (nrows > NRNG) nrows = NRNG;

    for (int i = tid; i < NRNG; i += 256) lcnt[i] = 0u;
    __syncthreads();

    // thread t <-> bin_a block t (ABLK == blockDim.x == 256)
    {
        const unsigned int c = cntm[(size_t)tid * NBUCK + nb];
        const unsigned int o = ofsm[(size_t)tid * NBUCK + nb];
        const uint2* __restrict__ run = &stage[(size_t)tid * RECCAP + o];
        for (unsigned int j = 0; j < c; ++j) {
            const uint2 rec = run[j];
            const int rl = (int)(rec.y & 127u);
            const unsigned int k = atomicAdd(&lcnt[rl], 1u);
            if (k < CAP) lists[(rl << 6) + k] = rec.x;
        }
    }
    __syncthreads();

    // coalesced stream-out (garbage slots beyond count are masked by gather)
    unsigned int* __restrict__ dst = &cvp[(size_t)row0 << 6];
    const int words = nrows << 6;
    for (int i = tid; i < words; i += 256) dst[i] = lists[i];
    for (int rl = tid; rl < nrows; rl += 256) {
        const unsigned int c = lcnt[rl];
        cntp[(size_t)(row0 + rl) * 16] = (int)(c < CAP ? c : CAP);
    }
}

// ---------------------------------------------------------------------------
// row_gather: XCD-affine half-row jobs. Fixed-CAP (64, line-aligned) layout:
// first 16 edge words (one 64 B line) have KNOWN addresses -> cvp[slot],
// cvp[8+slot], count all load in parallel; gather xrb speculatively; zero
// multiplier for slots >= count. Fused finalize: out = relu(self_pre + agg).
// ---------------------------------------------------------------------------
#define GATHP(W, PRED, ACC)                                                   \
    {                                                                         \
        const unsigned int w = (W);                                           \
        unsigned int col = w & 0x1FFFFu;                                      \
        col = (col < Nn) ? col : 0u;       /* clamp speculative garbage */    \
        const float vv = (PRED) ? __half2float(__ushort_as_half(              \
                             (unsigned short)(w >> 17))) : 0.0f;              \
        const uint4 raw = *(const uint4*)&xrb[(size_t)col * CCOMB + c0];      \
        ACC[0] = fmaf(vv, __uint_as_float(raw.x << 16),         ACC[0]);      \
        ACC[1] = fmaf(vv, __uint_as_float(raw.x & 0xffff0000u), ACC[1]);      \
        ACC[2] = fmaf(vv, __uint_as_float(raw.y << 16),         ACC[2]);      \
        ACC[3] = fmaf(vv, __uint_as_float(raw.y & 0xffff0000u), ACC[3]);      \
        ACC[4] = fmaf(vv, __uint_as_float(raw.z << 16),         ACC[4]);      \
        ACC[5] = fmaf(vv, __uint_as_float(raw.z & 0xffff0000u), ACC[5]);      \
        ACC[6] = fmaf(vv, __uint_as_float(raw.w << 16),         ACC[6]);      \
        ACC[7] = fmaf(vv, __uint_as_float(raw.w & 0xffff0000u), ACC[7]);      \
    }

__global__ __launch_bounds__(256) void row_gather(
    const int* __restrict__ cntp, const unsigned int* __restrict__ cvp,
    const unsigned short* __restrict__ xrb, float* __restrict__ outp)
{
    const int j    = blockIdx.x;
    const int low3 = j & 7;
    const int h    = (low3 >= 4) ? 1 : 0;      // batch half -> XCD group
    const int ord  = (j >> 3) * 4 + (low3 & 3);
    int n = ord * 4 + (threadIdx.x >> 6);
    n = __builtin_amdgcn_readfirstlane(n);     // wave-uniform -> scalar loads

    const int lane = threadIdx.x & 63;
    const int slot = lane >> 3;                // edge slot 0..7
    const int c0   = h * 64 + (lane & 7) * 8;  // 8 combined cols per lane
    const unsigned int* __restrict__ seg = &cvp[(size_t)n << 6];

    // three independent loads issue together
    const int kc = min(cntp[(size_t)n * 16], CAP);
    const unsigned int u0 = seg[slot];
    const unsigned int u1 = seg[8 + slot];

    float aA[8] = {0.f, 0.f, 0.f, 0.f, 0.f, 0.f, 0.f, 0.f};

    GATHP(u0, slot < kc,     aA);
    GATHP(u1, slot + 8 < kc, aA);

    for (int e = 16 + slot; e < kc; e += 8) {
        const unsigned int u = seg[e];
        GATHP(u, true, aA);
    }

#pragma unroll
    for (int i = 0; i < 8; ++i) {
        aA[i] += __shfl_down(aA[i], 8);
        aA[i] += __shfl_down(aA[i], 16);
        aA[i] += __shfl_down(aA[i], 32);
    }

    if (lane < 8) {
        const size_t m = (size_t)h * Nn + n;
        const int o = lane * 8;                // feature offset within 64
        float* __restrict__ op = &outp[m * FOUTc + o];
        float4 s0 = *(float4*)&op[0];
        float4 s1 = *(float4*)&op[4];
        s0.x = fmaxf(s0.x + aA[0], 0.0f); s0.y = fmaxf(s0.y + aA[1], 0.0f);
        s0.z = fmaxf(s0.z + aA[2], 0.0f); s0.w = fmaxf(s0.w + aA[3], 0.0f);
        s1.x = fmaxf(s1.x + aA[4], 0.0f); s1.y = fmaxf(s1.y + aA[5], 0.0f);
        s1.z = fmaxf(s1.z + aA[6], 0.0f); s1.w = fmaxf(s1.w + aA[7], 0.0f);
        *(float4*)&op[0] = s0;
        *(float4*)&op[4] = s1;
    }
}

extern "C" void kernel_launch(void* const* d_in, const int* in_sizes, int n_in,
                              void* d_out, int out_size, void* d_ws, size_t ws_size,
                              hipStream_t stream)
{
    const float* x    = (const float*)d_in[0];
    const float* W    = (const float*)d_in[1];
    const float* Ws   = (const float*)d_in[2];
    const float* bs   = (const float*)d_in[3];
    const int*   erow = (const int*)d_in[4];
    const int*   ecol = (const int*)d_in[5];
    const float* eval = (const float*)d_in[6];
    float* outp = (float*)d_out;
    const int E = in_sizes[4];

    // workspace layout (~36.2 MB total; all bases 8 B+ aligned by construction)
    unsigned short* xrb = (unsigned short*)d_ws;                      // 12.8 MB
    unsigned int*   cvp = (unsigned int*)(xrb + (size_t)Nn * CCOMB);  // 12.8 MB
    int*            cntp = (int*)(cvp + ((size_t)Nn << 6));           // 3.2 MB
    unsigned short* Bp  = (unsigned short*)(cntp + (size_t)Nn * 16);  // 32 KB
    unsigned int*   cntm = (unsigned int*)(Bp + 16384);               // 400 KB
    unsigned int*   ofsm = cntm + (size_t)ABLK * NBUCK;               // 400 KB
    uint2*          stage = (uint2*)(ofsm + (size_t)ABLK * NBUCK);    // 6.55 MB

    const int ec = (E + ABLK - 1) / ABLK;

    // 1. pack weights
    prep<<<8, 256, 0, stream>>>(W, Ws, Bp);

    // 2. fused: dense MFMA transform + atomic-free edge binning pass A
    gemm_bina<<<FUSED_GRID, 256, 0, stream>>>(x, Bp, bs, xrb, outp,
                                              erow, ecol, eval,
                                              cntm, ofsm, stage, E, ec);

    // 3. per-bucket gather from private chunks -> per-row CAP lists -> cvp/cntp
    bin_b<<<NBUCK, 256, 0, stream>>>(cntm, ofsm, stage, cvp, cntp);

    // 4. per-half-row speculative gather-reduce fused with finalize
    row_gather<<<Nn / 2, 256, 0, stream>>>(cntp, cvp, xrb, outp);
}